// Round 8
// baseline (960.018 us; speedup 1.0000x reference)
//
#include <hip/hip_runtime.h>
#include <hip/hip_bf16.h>

// Fused InverseResNet. Round 8 = R7 + MFMA SrcC hazard fence.
// R6(swizzle)/R7(linear) failed with IDENTICAL absmax 0.65625 -> LDS layout
// exonerated; deterministic common-mode bug. Theory: unprotected
// VALU-write -> asm-MFMA-SrcC-read hazard (needs 2 wait states, compiler
// doesn't see inside asm). R5 ran 2 waves/SIMD (other wave's slots covered
// the gap); R6/R7 run 1 wave/SIMD -> violation. Fix: s_nop 2 fence (accs
// tied) between acc init and first asm MFMA of each phase.

#define B_TOTAL 65536
#define LATENT  128
#define HIDDEN  256
#define OUTD    128
#define NBLOCKS 4
#define NITER   10
#define MTILE   64
#define LDSP    264   // row stride (elems); 528 B rows, 16B-aligned

typedef unsigned short u16;
typedef unsigned int   u32;
typedef u16    u16x4  __attribute__((ext_vector_type(4)));
typedef u16    u16x8  __attribute__((ext_vector_type(8)));
typedef __bf16 bf16x8 __attribute__((ext_vector_type(8)));
typedef float  f32x16 __attribute__((ext_vector_type(16)));

__device__ inline u16 f2b(float f){ __bf16 h=(__bf16)f; return __builtin_bit_cast(u16,h); }
__device__ inline u32 pk2(float lo, float hi){ return (u32)f2b(lo) | ((u32)f2b(hi)<<16); }

// All 256 weight AGPRs, clobbered on every asm touching them.
#define AGC \
 "a0","a1","a2","a3","a4","a5","a6","a7","a8","a9","a10","a11","a12","a13","a14","a15", \
 "a16","a17","a18","a19","a20","a21","a22","a23","a24","a25","a26","a27","a28","a29","a30","a31", \
 "a32","a33","a34","a35","a36","a37","a38","a39","a40","a41","a42","a43","a44","a45","a46","a47", \
 "a48","a49","a50","a51","a52","a53","a54","a55","a56","a57","a58","a59","a60","a61","a62","a63", \
 "a64","a65","a66","a67","a68","a69","a70","a71","a72","a73","a74","a75","a76","a77","a78","a79", \
 "a80","a81","a82","a83","a84","a85","a86","a87","a88","a89","a90","a91","a92","a93","a94","a95", \
 "a96","a97","a98","a99","a100","a101","a102","a103","a104","a105","a106","a107","a108","a109","a110","a111", \
 "a112","a113","a114","a115","a116","a117","a118","a119","a120","a121","a122","a123","a124","a125","a126","a127", \
 "a128","a129","a130","a131","a132","a133","a134","a135","a136","a137","a138","a139","a140","a141","a142","a143", \
 "a144","a145","a146","a147","a148","a149","a150","a151","a152","a153","a154","a155","a156","a157","a158","a159", \
 "a160","a161","a162","a163","a164","a165","a166","a167","a168","a169","a170","a171","a172","a173","a174","a175", \
 "a176","a177","a178","a179","a180","a181","a182","a183","a184","a185","a186","a187","a188","a189","a190","a191", \
 "a192","a193","a194","a195","a196","a197","a198","a199","a200","a201","a202","a203","a204","a205","a206","a207", \
 "a208","a209","a210","a211","a212","a213","a214","a215","a216","a217","a218","a219","a220","a221","a222","a223", \
 "a224","a225","a226","a227","a228","a229","a230","a231","a232","a233","a234","a235","a236","a237","a238","a239", \
 "a240","a241","a242","a243","a244","a245","a246","a247","a248","a249","a250","a251","a252","a253","a254","a255"

// Load one K-step weight fragment (8 rows of column COL) into 4 literal AGPRs.
#define LOADW(P, KS, NEG, COL, A0,A1,A2,A3) { \
  const float* _w = (P) + (size_t)((KS)*16 + hi*8)*HIDDEN + (COL); \
  float _v0=_w[0], _v1=_w[HIDDEN], _v2=_w[2*HIDDEN], _v3=_w[3*HIDDEN]; \
  float _v4=_w[4*HIDDEN], _v5=_w[5*HIDDEN], _v6=_w[6*HIDDEN], _v7=_w[7*HIDDEN]; \
  if (NEG){_v0=-_v0;_v1=-_v1;_v2=-_v2;_v3=-_v3;_v4=-_v4;_v5=-_v5;_v6=-_v6;_v7=-_v7;} \
  u32 _d0=pk2(_v0,_v1), _d1=pk2(_v2,_v3), _d2=pk2(_v4,_v5), _d3=pk2(_v6,_v7); \
  asm volatile("v_accvgpr_write_b32 a" #A0 ", %0\n\t" \
               "v_accvgpr_write_b32 a" #A1 ", %1\n\t" \
               "v_accvgpr_write_b32 a" #A2 ", %2\n\t" \
               "v_accvgpr_write_b32 a" #A3 ", %3" \
               :: "v"(_d0),"v"(_d1),"v"(_d2),"v"(_d3) : AGC); }

// One K-step: 2 b128 reads (rows lo, 32+lo) feed 4 MFMAs (2 col-slices).
#define STEPX(SRC, KS, P,Q, R,S) { \
  const int _off = rdA + (KS)*16; \
  bf16x8 _b0 = *(const bf16x8*)((SRC) + _off); \
  bf16x8 _b1 = *(const bf16x8*)((SRC) + 32*LDSP + _off); \
  asm volatile("v_mfma_f32_32x32x16_bf16 %0, a[" #P ":" #Q "], %1, %0" : "+v"(acc00) : "v"(_b0) : AGC); \
  asm volatile("v_mfma_f32_32x32x16_bf16 %0, a[" #P ":" #Q "], %1, %0" : "+v"(acc10) : "v"(_b1) : AGC); \
  asm volatile("v_mfma_f32_32x32x16_bf16 %0, a[" #R ":" #S "], %1, %0" : "+v"(acc01) : "v"(_b0) : AGC); \
  asm volatile("v_mfma_f32_32x32x16_bf16 %0, a[" #R ":" #S "], %1, %0" : "+v"(acc11) : "v"(_b1) : AGC); }

// VALU-write -> MFMA-SrcC-read hazard fence (2 wait states required; give 3).
// Must sit between the v_mov acc inits and the first asm MFMA of a phase.
#define ACCINIT_FENCE asm volatile("s_nop 2" \
  : "+v"(acc00), "+v"(acc01), "+v"(acc10), "+v"(acc11))

// MFMA-write -> VALU-read hazard fence (~18 wait states required; give 24).
#define ACCFENCE asm volatile("s_nop 7\n\ts_nop 7\n\ts_nop 7" \
  : "+v"(acc00), "+v"(acc01), "+v"(acc10), "+v"(acc11))

#define MFMA_I(a,b,c) __builtin_amdgcn_mfma_f32_32x32x16_bf16(a,b,c,0,0,0)

__device__ inline bf16x8 load_wfrag_f(const float* __restrict__ W, int ldw, int krow0,
                                      int col){
  bf16x8 r;
#pragma unroll
  for (int j=0;j<8;j++) r[j] = (__bf16)W[(size_t)(krow0+j)*ldw + col];
  return r;
}

// Store one C^T tile (16 vals) to row-major LDS: row=row_elem/LDSP,
// cols colb + 8q + {0..3} (colb = nb + 4*hi) -> 4x ds_write_b64.
__device__ inline void store_tile(u16* __restrict__ dst, int row_elem, int colb,
                                  const f32x16 a, bool relu){
#pragma unroll
  for (int q=0;q<4;q++){
    u16x4 p;
#pragma unroll
    for (int i=0;i<4;i++){
      float v = a[4*q+i];
      if (relu) v = v > 0.f ? v : 0.f;
      p[i] = f2b(v);
    }
    *(u16x4*)(dst + row_elem + colb + 8*q) = p;
  }
}

__global__
__attribute__((amdgpu_flat_work_group_size(256,256)))
__attribute__((amdgpu_waves_per_eu(1,1)))
void irn_kernel(const float* __restrict__ x,
                const float* __restrict__ Winit, const float* __restrict__ binit,
                const float* __restrict__ Wg1,   const float* __restrict__ bg1,
                const float* __restrict__ Wg2,   const float* __restrict__ bg2,
                const float* __restrict__ Wfin,  const float* __restrict__ bfin,
                float* __restrict__ out)
{
  __shared__ u16 Xb[MTILE*LDSP];
  __shared__ u16 Hb[MTILE*LDSP];

  const int tid = threadIdx.x;
  const int wv  = tid >> 6;      // wave 0..3 -> 64-col slice of HIDDEN
  const int ln  = tid & 63;
  const int lo  = ln & 31;
  const int hi  = ln >> 5;
  const int row0 = blockIdx.x * MTILE;
  const int nb0  = wv * 64;          // col-slice 0 base
  const int nb1  = nb0 + 32;         // col-slice 1 base
  const int colw0 = nb0 + lo;
  const int colw1 = nb1 + lo;

  const int rdA = lo*LDSP + 8*hi;    // activation read base (rows lo / 32+lo)
  const int cb0 = nb0 + 4*hi;        // store col bases
  const int cb1 = nb1 + 4*hi;

  // ---- stage x tile [64 x 128] fp32 -> bf16 into Xb ----
  {
    const int r  = tid >> 2;             // 0..63
    const int c0 = (tid & 3) * 32;       // 4 blocks of 8 elems
    const float4* src = (const float4*)(x + (size_t)(row0 + r)*LATENT + c0);
#pragma unroll
    for (int j=0;j<4;j++){
      float4 a = src[2*j], b = src[2*j+1];
      u16x8 p;
      p[0]=f2b(a.x); p[1]=f2b(a.y); p[2]=f2b(a.z); p[3]=f2b(a.w);
      p[4]=f2b(b.x); p[5]=f2b(b.y); p[6]=f2b(b.z); p[7]=f2b(b.w);
      *(u16x8*)(Xb + r*LDSP + c0 + 8*j) = p;
    }
  }

  f32x16 yv00, yv01, yv10, yv11;   // y (fp32), C^T layout per tile

  __syncthreads();

  // ---- initial GEMM: h^T = Winit^T @ x^T (K=128), intrinsics ----
  {
    bf16x8 wf0[8], wf1[8];
#pragma unroll
    for (int ks=0; ks<8; ks++){
      wf0[ks] = load_wfrag_f(Winit, HIDDEN, ks*16 + hi*8, colw0);
      wf1[ks] = load_wfrag_f(Winit, HIDDEN, ks*16 + hi*8, colw1);
    }
    f32x16 acc00, acc01, acc10, acc11;
#pragma unroll
    for (int r=0;r<16;r++){
      const int c = (r&3) + 8*(r>>2) + 4*hi;
      acc00[r]=binit[nb0+c]; acc01[r]=binit[nb1+c];
      acc10[r]=acc00[r];     acc11[r]=acc01[r];
    }
#pragma unroll
    for (int ks=0; ks<8; ks++){
      const int off = rdA + ks*16;
      bf16x8 b0 = *(const bf16x8*)(Xb + off);
      bf16x8 b1 = *(const bf16x8*)(Xb + 32*LDSP + off);
      acc00=MFMA_I(wf0[ks], b0, acc00);
      acc10=MFMA_I(wf0[ks], b1, acc10);
      acc01=MFMA_I(wf1[ks], b0, acc01);
      acc11=MFMA_I(wf1[ks], b1, acc11);
    }
    __syncthreads();   // all reads of Xb done before overwrite
    store_tile(Xb, (0 +lo)*LDSP, cb0, acc00, false);
    store_tile(Xb, (0 +lo)*LDSP, cb1, acc01, false);
    store_tile(Xb, (32+lo)*LDSP, cb0, acc10, false);
    store_tile(Xb, (32+lo)*LDSP, cb1, acc11, false);
    yv00=acc00; yv01=acc01; yv10=acc10; yv11=acc11;
    __syncthreads();
  }

  // ---- 4 blocks x 10 fixed-point iterations ----
#pragma unroll 1
  for (int b=0; b<NBLOCKS; b++){
    const float* W1p = Wg1 + (size_t)b*HIDDEN*HIDDEN;
    const float* W2p = Wg2 + (size_t)b*HIDDEN*HIDDEN;

    // W1 slice0 -> a0..a63
    LOADW(W1p, 0,0,colw0,  0,1,2,3)     LOADW(W1p, 1,0,colw0,  4,5,6,7)
    LOADW(W1p, 2,0,colw0,  8,9,10,11)   LOADW(W1p, 3,0,colw0,  12,13,14,15)
    LOADW(W1p, 4,0,colw0,  16,17,18,19) LOADW(W1p, 5,0,colw0,  20,21,22,23)
    LOADW(W1p, 6,0,colw0,  24,25,26,27) LOADW(W1p, 7,0,colw0,  28,29,30,31)
    LOADW(W1p, 8,0,colw0,  32,33,34,35) LOADW(W1p, 9,0,colw0,  36,37,38,39)
    LOADW(W1p,10,0,colw0,  40,41,42,43) LOADW(W1p,11,0,colw0,  44,45,46,47)
    LOADW(W1p,12,0,colw0,  48,49,50,51) LOADW(W1p,13,0,colw0,  52,53,54,55)
    LOADW(W1p,14,0,colw0,  56,57,58,59) LOADW(W1p,15,0,colw0,  60,61,62,63)
    // W1 slice1 -> a64..a127
    LOADW(W1p, 0,0,colw1,  64,65,66,67)     LOADW(W1p, 1,0,colw1,  68,69,70,71)
    LOADW(W1p, 2,0,colw1,  72,73,74,75)     LOADW(W1p, 3,0,colw1,  76,77,78,79)
    LOADW(W1p, 4,0,colw1,  80,81,82,83)     LOADW(W1p, 5,0,colw1,  84,85,86,87)
    LOADW(W1p, 6,0,colw1,  88,89,90,91)     LOADW(W1p, 7,0,colw1,  92,93,94,95)
    LOADW(W1p, 8,0,colw1,  96,97,98,99)     LOADW(W1p, 9,0,colw1,  100,101,102,103)
    LOADW(W1p,10,0,colw1,  104,105,106,107) LOADW(W1p,11,0,colw1,  108,109,110,111)
    LOADW(W1p,12,0,colw1,  112,113,114,115) LOADW(W1p,13,0,colw1,  116,117,118,119)
    LOADW(W1p,14,0,colw1,  120,121,122,123) LOADW(W1p,15,0,colw1,  124,125,126,127)
    // -W2 slice0 -> a128..a191
    LOADW(W2p, 0,1,colw0,  128,129,130,131) LOADW(W2p, 1,1,colw0,  132,133,134,135)
    LOADW(W2p, 2,1,colw0,  136,137,138,139) LOADW(W2p, 3,1,colw0,  140,141,142,143)
    LOADW(W2p, 4,1,colw0,  144,145,146,147) LOADW(W2p, 5,1,colw0,  148,149,150,151)
    LOADW(W2p, 6,1,colw0,  152,153,154,155) LOADW(W2p, 7,1,colw0,  156,157,158,159)
    LOADW(W2p, 8,1,colw0,  160,161,162,163) LOADW(W2p, 9,1,colw0,  164,165,166,167)
    LOADW(W2p,10,1,colw0,  168,169,170,171) LOADW(W2p,11,1,colw0,  172,173,174,175)
    LOADW(W2p,12,1,colw0,  176,177,178,179) LOADW(W2p,13,1,colw0,  180,181,182,183)
    LOADW(W2p,14,1,colw0,  184,185,186,187) LOADW(W2p,15,1,colw0,  188,189,190,191)
    // -W2 slice1 -> a192..a255
    LOADW(W2p, 0,1,colw1,  192,193,194,195) LOADW(W2p, 1,1,colw1,  196,197,198,199)
    LOADW(W2p, 2,1,colw1,  200,201,202,203) LOADW(W2p, 3,1,colw1,  204,205,206,207)
    LOADW(W2p, 4,1,colw1,  208,209,210,211) LOADW(W2p, 5,1,colw1,  212,213,214,215)
    LOADW(W2p, 6,1,colw1,  216,217,218,219) LOADW(W2p, 7,1,colw1,  220,221,222,223)
    LOADW(W2p, 8,1,colw1,  224,225,226,227) LOADW(W2p, 9,1,colw1,  228,229,230,231)
    LOADW(W2p,10,1,colw1,  232,233,234,235) LOADW(W2p,11,1,colw1,  236,237,238,239)
    LOADW(W2p,12,1,colw1,  240,241,242,243) LOADW(W2p,13,1,colw1,  244,245,246,247)
    LOADW(W2p,14,1,colw1,  248,249,250,251) LOADW(W2p,15,1,colw1,  252,253,254,255)
    asm volatile("s_nop 3" :::);   // accvgpr_write -> MFMA-read wait states

    // biases (fp32): b1 vectors; fold b2 into y
    f32x16 b1v0, b1v1;
    {
      const float* b1g = bg1 + b*HIDDEN;
      const float* b2g = bg2 + b*HIDDEN;
#pragma unroll
      for (int r=0;r<16;r++){
        const int c = (r&3) + 8*(r>>2) + 4*hi;
        b1v0[r] = b1g[nb0+c];  b1v1[r] = b1g[nb1+c];
        const float b20 = b2g[nb0+c], b21 = b2g[nb1+c];
        yv00[r] -= b20; yv10[r] -= b20;
        yv01[r] -= b21; yv11[r] -= b21;
      }
    }

#pragma unroll 1
    for (int it=0; it<NITER; it++){
      { // phase 1: H = relu(X @ W1 + b1)
        f32x16 acc00=b1v0, acc01=b1v1, acc10=b1v0, acc11=b1v1;
        ACCINIT_FENCE;   // VALU-write -> MFMA SrcC-read hazard
        STEPX(Xb, 0,  0,3,   64,67)   STEPX(Xb, 1,  4,7,   68,71)
        STEPX(Xb, 2,  8,11,  72,75)   STEPX(Xb, 3,  12,15, 76,79)
        STEPX(Xb, 4,  16,19, 80,83)   STEPX(Xb, 5,  20,23, 84,87)
        STEPX(Xb, 6,  24,27, 88,91)   STEPX(Xb, 7,  28,31, 92,95)
        STEPX(Xb, 8,  32,35, 96,99)   STEPX(Xb, 9,  36,39, 100,103)
        STEPX(Xb,10,  40,43, 104,107) STEPX(Xb,11,  44,47, 108,111)
        STEPX(Xb,12,  48,51, 112,115) STEPX(Xb,13,  52,55, 116,119)
        STEPX(Xb,14,  56,59, 120,123) STEPX(Xb,15,  60,63, 124,127)
        ACCFENCE;
        store_tile(Hb, (0 +lo)*LDSP, cb0, acc00, true);
        store_tile(Hb, (0 +lo)*LDSP, cb1, acc01, true);
        store_tile(Hb, (32+lo)*LDSP, cb0, acc10, true);
        store_tile(Hb, (32+lo)*LDSP, cb1, acc11, true);
      }
      __syncthreads();
      { // phase 2: Xnew = (y - b2) + H @ (-W2)
        f32x16 acc00=yv00, acc01=yv01, acc10=yv10, acc11=yv11;
        ACCINIT_FENCE;   // VALU-write -> MFMA SrcC-read hazard
        STEPX(Hb, 0,  128,131, 192,195) STEPX(Hb, 1,  132,135, 196,199)
        STEPX(Hb, 2,  136,139, 200,203) STEPX(Hb, 3,  140,143, 204,207)
        STEPX(Hb, 4,  144,147, 208,211) STEPX(Hb, 5,  148,151, 212,215)
        STEPX(Hb, 6,  152,155, 216,219) STEPX(Hb, 7,  156,159, 220,223)
        STEPX(Hb, 8,  160,163, 224,227) STEPX(Hb, 9,  164,167, 228,231)
        STEPX(Hb,10,  168,171, 232,235) STEPX(Hb,11,  172,175, 236,239)
        STEPX(Hb,12,  176,179, 240,243) STEPX(Hb,13,  180,183, 244,247)
        STEPX(Hb,14,  184,187, 248,251) STEPX(Hb,15,  188,191, 252,255)
        ACCFENCE;
        store_tile(Xb, (0 +lo)*LDSP, cb0, acc00, false);
        store_tile(Xb, (0 +lo)*LDSP, cb1, acc01, false);
        store_tile(Xb, (32+lo)*LDSP, cb0, acc10, false);
        store_tile(Xb, (32+lo)*LDSP, cb1, acc11, false);
        if (it == NITER-1){ yv00=acc00; yv01=acc01; yv10=acc10; yv11=acc11; }
      }
      __syncthreads();
    }
  }

  // ---- final GEMM: out^T = Wfin^T @ X^T (N=128 -> 4 waves x 32 cols) ----
  {
    const int colf = wv*32 + lo;
    bf16x8 wf[16];
#pragma unroll
    for (int ks=0; ks<16; ks++)
      wf[ks] = load_wfrag_f(Wfin, OUTD, ks*16 + hi*8, colf);
    f32x16 acc0, acc1;
#pragma unroll
    for (int r=0;r<16;r++){
      const float bv = bfin[wv*32 + (r&3) + 8*(r>>2) + 4*hi];
      acc0[r]=bv; acc1[r]=bv;
    }
#pragma unroll
    for (int ks=0; ks<16; ks++){
      const int off = rdA + ks*16;
      bf16x8 b0 = *(const bf16x8*)(Xb + off);
      bf16x8 b1 = *(const bf16x8*)(Xb + 32*LDSP + off);
      acc0 = MFMA_I(wf[ks], b0, acc0);
      acc1 = MFMA_I(wf[ks], b1, acc1);
    }
    float* orow0 = out + (size_t)(row0 + lo)*OUTD + wv*32;
    float* orow1 = out + (size_t)(row0 + 32 + lo)*OUTD + wv*32;
#pragma unroll
    for (int q=0;q<4;q++){
      *(float4*)(orow0 + 8*q + 4*hi) = make_float4(acc0[4*q],acc0[4*q+1],acc0[4*q+2],acc0[4*q+3]);
      *(float4*)(orow1 + 8*q + 4*hi) = make_float4(acc1[4*q],acc1[4*q+1],acc1[4*q+2],acc1[4*q+3]);
    }
  }
}

extern "C" void kernel_launch(void* const* d_in, const int* in_sizes, int n_in,
                              void* d_out, int out_size, void* d_ws, size_t ws_size,
                              hipStream_t stream) {
  (void)in_sizes; (void)n_in; (void)d_ws; (void)ws_size; (void)out_size;
  const float* x     = (const float*)d_in[0];
  const float* Winit = (const float*)d_in[1];
  const float* binit = (const float*)d_in[2];
  const float* Wg1   = (const float*)d_in[3];
  const float* bg1   = (const float*)d_in[4];
  const float* Wg2   = (const float*)d_in[5];
  const float* bg2   = (const float*)d_in[6];
  const float* Wfin  = (const float*)d_in[7];
  const float* bfin  = (const float*)d_in[8];
  float* out = (float*)d_out;
  irn_kernel<<<dim3(B_TOTAL/MTILE), dim3(256), 0, stream>>>(
      x, Winit, binit, Wg1, bg1, Wg2, bg2, Wfin, bfin, out);
}